// Round 6
// baseline (382.065 us; speedup 1.0000x reference)
//
#include <hip/hip_runtime.h>
#include <hip/hip_bf16.h>

#define N_NODES 50000
#define N_EDGES 800000
#define D_IN 128
#define D_H 64
#define NB 64          // buckets, dst >> 10
#define BCAP 96        // LDS staging capacity per bucket per round
#define BSTRIDE 32768  // per-bucket region in bpairs (avg fill ~16.3K, +120 sigma safe)

typedef short bf16x8 __attribute__((ext_vector_type(8)));
typedef float f32x4 __attribute__((ext_vector_type(4)));

__device__ __forceinline__ ushort f2bf(float f) {
    __hip_bfloat16 b = __float2bfloat16(f);
    return *reinterpret_cast<ushort*>(&b);
}
__device__ __forceinline__ float bf16_lo(unsigned int u) { return __uint_as_float(u << 16); }
__device__ __forceinline__ float bf16_hi(unsigned int u) { return __uint_as_float(u & 0xffff0000u); }

// ---------- CSR build, phase A: bucket edges by dst>>10 with LDS staging ----------
// packed word: src (16 bits, src<50000<65536) | local dst (10 bits) << 16
__global__ void bucketA_kernel(const int* __restrict__ srcv, const int* __restrict__ dstv,
                               int* __restrict__ gcur, unsigned int* __restrict__ bpairs) {
    __shared__ int bcnt[NB];
    __shared__ unsigned int bbuf[NB][BCAP];
    int t = threadIdx.x;
    const int EPB = (N_EDGES + gridDim.x - 1) / gridDim.x;
    int e0 = blockIdx.x * EPB;
    int e1 = e0 + EPB; if (e1 > N_EDGES) e1 = N_EDGES;

    for (int base = e0; base < e1; base += 2048) {
        if (t < NB) bcnt[t] = 0;
        __syncthreads();
        int lim = base + 2048; if (lim > e1) lim = e1;
        for (int e = base + t; e < lim; e += 256) {
            int s = srcv[e], d = dstv[e];
            int b = d >> 10;
            unsigned int w = (unsigned int)s | ((unsigned int)(d & 1023) << 16);
            int pos = atomicAdd(&bcnt[b], 1);
            if (pos < BCAP) bbuf[b][pos] = w;
            else {  // rare spill: direct global append
                int gp = atomicAdd(&gcur[b], 1);
                bpairs[b * BSTRIDE + gp] = w;
            }
        }
        __syncthreads();
        int wid = t >> 6, lane = t & 63;
        for (int b = wid * 16; b < wid * 16 + 16; ++b) {
            int n = bcnt[b]; if (n > BCAP) n = BCAP;
            if (n == 0) continue;
            int gbase = 0;
            if (lane == 0) gbase = atomicAdd(&gcur[b], n);
            gbase = __shfl(gbase, 0);
            for (int i = lane; i < n; i += 64)
                bpairs[b * BSTRIDE + gbase + i] = bbuf[b][i];
        }
        __syncthreads();
    }
}

// ---------- exclusive scan of 64 bucket counts ----------
__global__ void bucket_scan_kernel(const int* __restrict__ gcur, int* __restrict__ bucket_base) {
    int t = threadIdx.x;  // 64 threads
    int c = gcur[t];
    int v = c;
    for (int off = 1; off < 64; off <<= 1) {
        int u = __shfl_up(v, off);
        if (t >= off) v += u;
    }
    bucket_base[t] = v - c;
}

// ---------- CSR build, phase B: per-bucket hist + scan + local scatter ----------
__global__ void __launch_bounds__(1024) bucketB_kernel(const int* __restrict__ gcur,
                                                       const int* __restrict__ bucket_base,
                                                       const unsigned int* __restrict__ bpairs,
                                                       int* __restrict__ row_ptr,
                                                       int* __restrict__ csr_src) {
    __shared__ int lcnt[1024];
    __shared__ int lptr[1024];
    __shared__ int wsum[16];
    int b = blockIdx.x;
    int t = threadIdx.x;
    int n = gcur[b];
    int base = bucket_base[b];
    lcnt[t] = 0;
    __syncthreads();
    const unsigned int* __restrict__ bp = bpairs + (size_t)b * BSTRIDE;
    for (int i = t; i < n; i += 1024)
        atomicAdd(&lcnt[bp[i] >> 16], 1);
    __syncthreads();
    // block exclusive scan over 1024 counts
    int v = lcnt[t];
    int lane = t & 63, wid = t >> 6;
    int inc = v;
    for (int off = 1; off < 64; off <<= 1) {
        int u = __shfl_up(inc, off);
        if (lane >= off) inc += u;
    }
    if (lane == 63) wsum[wid] = inc;
    __syncthreads();
    if (t < 16) {
        int s = wsum[t];
        for (int off = 1; off < 16; off <<= 1) {
            int u = __shfl_up(s, off);
            if (t >= off) s += u;
        }
        wsum[t] = s;
    }
    __syncthreads();
    int excl = ((wid > 0) ? wsum[wid - 1] : 0) + inc - v;
    int node = (b << 10) + t;
    if (node <= N_NODES) row_ptr[node] = base + excl;
    lptr[t] = base + excl;
    __syncthreads();
    for (int i = t; i < n; i += 1024) {
        unsigned int w = bp[i];
        int p = atomicAdd(&lptr[w >> 16], 1);
        csr_src[p] = (int)(w & 0xFFFFu);
    }
}

// ---------- Y = bf16(h @ Wl), Z = f32(h @ Wr) via MFMA, fp32 input ----------
template <int FIN>
__global__ void linYZ_kernel(const float* __restrict__ h, const float* __restrict__ Wl,
                             const float* __restrict__ Wr,
                             ushort* __restrict__ Y, float* __restrict__ Z) {
    constexpr int KT = FIN / 32;
    int wave = (blockIdx.x * 256 + threadIdx.x) >> 6;
    int lane = threadIdx.x & 63;
    int col = lane & 15;
    int quad = lane >> 4;
    int nwaves = gridDim.x * 4;

    bf16x8 bl_frag[KT][4], br_frag[KT][4];
#pragma unroll
    for (int kt = 0; kt < KT; ++kt)
#pragma unroll
        for (int nt = 0; nt < 4; ++nt) {
            bf16x8 tl, tr;
#pragma unroll
            for (int j = 0; j < 8; ++j) {
                int row = kt * 32 + quad * 8 + j;
                tl[j] = (short)f2bf(Wl[row * D_H + nt * 16 + col]);
                tr[j] = (short)f2bf(Wr[row * D_H + nt * 16 + col]);
            }
            bl_frag[kt][nt] = tl;
            br_frag[kt][nt] = tr;
        }

    for (int m0 = wave * 16; m0 < N_NODES; m0 += nwaves * 16) {
        f32x4 accl0 = {0.f,0.f,0.f,0.f}, accl1 = accl0, accl2 = accl0, accl3 = accl0;
        f32x4 accr0 = accl0, accr1 = accl0, accr2 = accl0, accr3 = accl0;
        const float* arow = h + (size_t)(m0 + col) * FIN + quad * 8;
#pragma unroll
        for (int kt = 0; kt < KT; ++kt) {
            float4 a_lo = *reinterpret_cast<const float4*>(arow + kt * 32);
            float4 a_hi = *reinterpret_cast<const float4*>(arow + kt * 32 + 4);
            bf16x8 a;
            a[0] = (short)f2bf(a_lo.x); a[1] = (short)f2bf(a_lo.y);
            a[2] = (short)f2bf(a_lo.z); a[3] = (short)f2bf(a_lo.w);
            a[4] = (short)f2bf(a_hi.x); a[5] = (short)f2bf(a_hi.y);
            a[6] = (short)f2bf(a_hi.z); a[7] = (short)f2bf(a_hi.w);
            accl0 = __builtin_amdgcn_mfma_f32_16x16x32_bf16(a, bl_frag[kt][0], accl0, 0, 0, 0);
            accl1 = __builtin_amdgcn_mfma_f32_16x16x32_bf16(a, bl_frag[kt][1], accl1, 0, 0, 0);
            accl2 = __builtin_amdgcn_mfma_f32_16x16x32_bf16(a, bl_frag[kt][2], accl2, 0, 0, 0);
            accl3 = __builtin_amdgcn_mfma_f32_16x16x32_bf16(a, bl_frag[kt][3], accl3, 0, 0, 0);
            accr0 = __builtin_amdgcn_mfma_f32_16x16x32_bf16(a, br_frag[kt][0], accr0, 0, 0, 0);
            accr1 = __builtin_amdgcn_mfma_f32_16x16x32_bf16(a, br_frag[kt][1], accr1, 0, 0, 0);
            accr2 = __builtin_amdgcn_mfma_f32_16x16x32_bf16(a, br_frag[kt][2], accr2, 0, 0, 0);
            accr3 = __builtin_amdgcn_mfma_f32_16x16x32_bf16(a, br_frag[kt][3], accr3, 0, 0, 0);
        }
#pragma unroll
        for (int reg = 0; reg < 4; ++reg) {
            size_t r = (size_t)(m0 + quad * 4 + reg) * D_H;
            ushort* yp = Y + r;
            yp[0 * 16 + col] = f2bf(accl0[reg]);
            yp[1 * 16 + col] = f2bf(accl1[reg]);
            yp[2 * 16 + col] = f2bf(accl2[reg]);
            yp[3 * 16 + col] = f2bf(accl3[reg]);
            float* zp = Z + r;
            zp[0 * 16 + col] = accr0[reg];
            zp[1 * 16 + col] = accr1[reg];
            zp[2 * 16 + col] = accr2[reg];
            zp[3 * 16 + col] = accr3[reg];
        }
    }
}

// ---------- per-node: agg = mean_{src} Y[src]; out = elu(agg + bl + Z[node]) ----------
// FUSE_PROJ: layer-3 variant also emits ps = out@Wp_top, pd = out@Wp_bot
template <bool FUSE_PROJ>
__global__ void gather_kernel(const ushort* __restrict__ Y, const float* __restrict__ Z,
                              const float* __restrict__ bl,
                              const int* __restrict__ row_ptr, const int* __restrict__ csr_src,
                              float* __restrict__ out,
                              const float* __restrict__ Wp,
                              float* __restrict__ ps, float* __restrict__ pd) {
    int node = (blockIdx.x << 2) + (threadIdx.x >> 6);
    int lane = threadIdx.x & 63;
    if (node >= N_NODES) return;
    int g = lane >> 4;
    int l = lane & 15;

    int beg = row_ptr[node];
    int deg = row_ptr[node + 1] - beg;
    float a0 = 0.f, a1 = 0.f, a2 = 0.f, a3 = 0.f;
    const uint2* __restrict__ Y2 = reinterpret_cast<const uint2*>(Y);  // 16 uint2 per row

    for (int base = 0; base < deg; base += 64) {
        int wend = deg - base; if (wend > 64) wend = 64;
        int mye = base + lane;
        int idxv = (mye < deg) ? csr_src[beg + mye] : 0;
        for (int k = 0; k < wend; k += 16) {
            int e0 = k + g, e1 = k + 4 + g, e2 = k + 8 + g, e3 = k + 12 + g;
            int s0 = __shfl(idxv, e0);
            int s1 = __shfl(idxv, e1);
            int s2 = __shfl(idxv, e2);
            int s3 = __shfl(idxv, e3);
            bool v0 = e0 < wend, v1 = e1 < wend, v2 = e2 < wend, v3 = e3 < wend;
            uint2 r0, r1, r2, r3;
            if (v0) r0 = Y2[s0 * 16 + l];
            if (v1) r1 = Y2[s1 * 16 + l];
            if (v2) r2 = Y2[s2 * 16 + l];
            if (v3) r3 = Y2[s3 * 16 + l];
            if (v0) { a0 += bf16_lo(r0.x); a1 += bf16_hi(r0.x); a2 += bf16_lo(r0.y); a3 += bf16_hi(r0.y); }
            if (v1) { a0 += bf16_lo(r1.x); a1 += bf16_hi(r1.x); a2 += bf16_lo(r1.y); a3 += bf16_hi(r1.y); }
            if (v2) { a0 += bf16_lo(r2.x); a1 += bf16_hi(r2.x); a2 += bf16_lo(r2.y); a3 += bf16_hi(r2.y); }
            if (v3) { a0 += bf16_lo(r3.x); a1 += bf16_hi(r3.x); a2 += bf16_lo(r3.y); a3 += bf16_hi(r3.y); }
        }
    }

    a0 += __shfl_xor(a0, 16); a0 += __shfl_xor(a0, 32);
    a1 += __shfl_xor(a1, 16); a1 += __shfl_xor(a1, 32);
    a2 += __shfl_xor(a2, 16); a2 += __shfl_xor(a2, 32);
    a3 += __shfl_xor(a3, 16); a3 += __shfl_xor(a3, 32);

    if (g == 0) {
        float inv = 1.0f / fmaxf((float)deg, 1.0f);
        float4 b = reinterpret_cast<const float4*>(bl)[l];
        float4 zv = reinterpret_cast<const float4*>(Z + (size_t)node * D_H)[l];
        float v0 = a0 * inv + b.x + zv.x;
        float v1 = a1 * inv + b.y + zv.y;
        float v2 = a2 * inv + b.z + zv.z;
        float v3 = a3 * inv + b.w + zv.w;
        float4 o;
        o.x = v0 > 0.f ? v0 : expm1f(v0);
        o.y = v1 > 0.f ? v1 : expm1f(v1);
        o.z = v2 > 0.f ? v2 : expm1f(v2);
        o.w = v3 > 0.f ? v3 : expm1f(v3);
        reinterpret_cast<float4*>(out + (size_t)node * D_H)[l] = o;

        if (FUSE_PROJ) {
            // partials over k in {4l..4l+3} for the 4 output cols, both halves of Wp
            float p0 = 0.f, p1 = 0.f, p2 = 0.f, p3 = 0.f;
            float q0 = 0.f, q1 = 0.f, q2 = 0.f, q3 = 0.f;
            float ov[4] = {o.x, o.y, o.z, o.w};
#pragma unroll
            for (int j = 0; j < 4; ++j) {
                int k = 4 * l + j;
                float4 wt = reinterpret_cast<const float4*>(Wp)[k];         // Wp[k][0..3]
                float4 wb = reinterpret_cast<const float4*>(Wp)[D_H + k];   // Wp[64+k][0..3]
                p0 += ov[j] * wt.x; p1 += ov[j] * wt.y; p2 += ov[j] * wt.z; p3 += ov[j] * wt.w;
                q0 += ov[j] * wb.x; q1 += ov[j] * wb.y; q2 += ov[j] * wb.z; q3 += ov[j] * wb.w;
            }
#pragma unroll
            for (int off = 1; off < 16; off <<= 1) {
                p0 += __shfl_xor(p0, off); p1 += __shfl_xor(p1, off);
                p2 += __shfl_xor(p2, off); p3 += __shfl_xor(p3, off);
                q0 += __shfl_xor(q0, off); q1 += __shfl_xor(q1, off);
                q2 += __shfl_xor(q2, off); q3 += __shfl_xor(q3, off);
            }
            if (l == 0) {
                float4 pv; pv.x = p0; pv.y = p1; pv.z = p2; pv.w = p3;
                float4 qv; qv.x = q0; qv.y = q1; qv.z = q2; qv.w = q3;
                reinterpret_cast<float4*>(ps)[node] = pv;
                reinterpret_cast<float4*>(pd)[node] = qv;
            }
        }
    }
}

__global__ void edge_final_kernel(const int* __restrict__ srcv, const int* __restrict__ dstv,
                                  const float* __restrict__ ps, const float* __restrict__ pd,
                                  const float* __restrict__ bp, float* __restrict__ out) {
    int e = blockIdx.x * 256 + threadIdx.x;
    if (e >= N_EDGES) return;
    float4 a = reinterpret_cast<const float4*>(ps)[srcv[e]];
    float4 b = reinterpret_cast<const float4*>(pd)[dstv[e]];
    float4 o;
    o.x = a.x + b.x + bp[0];
    o.y = a.y + b.y + bp[1];
    o.z = a.z + b.z + bp[2];
    o.w = a.w + b.w + bp[3];
    reinterpret_cast<float4*>(out)[e] = o;
}

extern "C" void kernel_launch(void* const* d_in, const int* in_sizes, int n_in,
                              void* d_out, int out_size, void* d_ws, size_t ws_size,
                              hipStream_t stream) {
    const float* x   = (const float*)d_in[0];
    const int*   ei  = (const int*)d_in[1];
    const float* Wl1 = (const float*)d_in[2];
    const float* bl1 = (const float*)d_in[3];
    const float* Wr1 = (const float*)d_in[4];
    const float* Wl2 = (const float*)d_in[5];
    const float* bl2 = (const float*)d_in[6];
    const float* Wr2 = (const float*)d_in[7];
    const float* Wl3 = (const float*)d_in[8];
    const float* bl3 = (const float*)d_in[9];
    const float* Wr3 = (const float*)d_in[10];
    const float* Wp  = (const float*)d_in[11];
    const float* bp  = (const float*)d_in[12];
    float* out = (float*)d_out;

    const int* srcv = ei;
    const int* dstv = ei + N_EDGES;

    // ---- workspace carve-up ----
    int* gcur        = (int*)d_ws;                       // 64
    int* bucket_base = gcur + 64;                        // 64
    int* row_ptr     = bucket_base + 64;                 // 50001
    int* csr_src     = row_ptr + 50001;                  // 800000
    unsigned int* bpairs = (unsigned int*)(((uintptr_t)(csr_src + 800000) + 127) & ~(uintptr_t)127);
    ushort* Y = (ushort*)(((uintptr_t)(bpairs + (size_t)NB * BSTRIDE) + 127) & ~(uintptr_t)127);
    float* Z  = (float*)(((uintptr_t)(Y + (size_t)N_NODES * D_H) + 15) & ~(uintptr_t)15);
    float* H1 = Z + (size_t)N_NODES * D_H;
    float* H2 = H1 + (size_t)N_NODES * D_H;
    float* ps = H2 + (size_t)N_NODES * D_H;
    float* pd = ps + (size_t)N_NODES * 4;

    // ---- CSR build (bucketed, 3 kernels) ----
    hipMemsetAsync(gcur, 0, NB * sizeof(int), stream);
    bucketA_kernel<<<256, 256, 0, stream>>>(srcv, dstv, gcur, bpairs);
    bucket_scan_kernel<<<1, 64, 0, stream>>>(gcur, bucket_base);
    bucketB_kernel<<<NB, 1024, 0, stream>>>(gcur, bucket_base, bpairs, row_ptr, csr_src);

    const int GATHER_GRID = (N_NODES + 3) / 4;
    const int MFMA_GRID = 256;

    // ---- layer 1 (FIN=128) ----
    linYZ_kernel<D_IN><<<MFMA_GRID, 256, 0, stream>>>(x, Wl1, Wr1, Y, Z);
    gather_kernel<false><<<GATHER_GRID, 256, 0, stream>>>(Y, Z, bl1, row_ptr, csr_src, H1,
                                                          nullptr, nullptr, nullptr);

    // ---- layer 2 (FIN=64) ----
    linYZ_kernel<D_H><<<MFMA_GRID, 256, 0, stream>>>(H1, Wl2, Wr2, Y, Z);
    gather_kernel<false><<<GATHER_GRID, 256, 0, stream>>>(Y, Z, bl2, row_ptr, csr_src, H2,
                                                          nullptr, nullptr, nullptr);

    // ---- layer 3 (FIN=64), fused output projection ----
    linYZ_kernel<D_H><<<MFMA_GRID, 256, 0, stream>>>(H2, Wl3, Wr3, Y, Z);
    gather_kernel<true><<<GATHER_GRID, 256, 0, stream>>>(Y, Z, bl3, row_ptr, csr_src, H1,
                                                         Wp, ps, pd);

    // ---- edge output: out[e] = ps[src] + pd[dst] + bp ----
    edge_final_kernel<<<(N_EDGES + 255) / 256, 256, 0, stream>>>(srcv, dstv, ps, pd, bp, out);
}

// Round 7
// 338.106 us; speedup vs baseline: 1.1300x; 1.1300x over previous
//
#include <hip/hip_runtime.h>
#include <hip/hip_bf16.h>

#define N_NODES 50000
#define N_EDGES 800000
#define D_IN 128
#define D_H 64
#define SCAN_BLOCKS 196   // ceil(50000/256)

typedef short bf16x8 __attribute__((ext_vector_type(8)));
typedef float f32x4 __attribute__((ext_vector_type(4)));

__device__ __forceinline__ ushort f2bf(float f) {
    __hip_bfloat16 b = __float2bfloat16(f);
    return *reinterpret_cast<ushort*>(&b);
}
__device__ __forceinline__ float bf16_lo(unsigned int u) { return __uint_as_float(u << 16); }
__device__ __forceinline__ float bf16_hi(unsigned int u) { return __uint_as_float(u & 0xffff0000u); }

// ---------- CSR build (round-5 proven path) ----------
__global__ void hist_kernel(const int* __restrict__ dstv, int* __restrict__ cnt) {
    int e = blockIdx.x * 256 + threadIdx.x;
    if (e < N_EDGES) atomicAdd(&cnt[dstv[e]], 1);
}

__global__ void scan_partial(const int* __restrict__ cnt, int* __restrict__ blockSums) {
    __shared__ int s[256];
    int i = blockIdx.x * 256 + threadIdx.x;
    s[threadIdx.x] = (i < N_NODES) ? cnt[i] : 0;
    __syncthreads();
    for (int off = 128; off > 0; off >>= 1) {
        if (threadIdx.x < off) s[threadIdx.x] += s[threadIdx.x + off];
        __syncthreads();
    }
    if (threadIdx.x == 0) blockSums[blockIdx.x] = s[0];
}

__global__ void scan_sums(int* __restrict__ blockSums) {
    __shared__ int s[256];
    int t = threadIdx.x;
    s[t] = (t < SCAN_BLOCKS) ? blockSums[t] : 0;
    __syncthreads();
    for (int off = 1; off < 256; off <<= 1) {
        int tmp = (t >= off) ? s[t - off] : 0;
        __syncthreads();
        s[t] += tmp;
        __syncthreads();
    }
    if (t < SCAN_BLOCKS) blockSums[t] = (t > 0) ? s[t - 1] : 0;
}

__global__ void scan_final(const int* __restrict__ cnt, const int* __restrict__ blockSums,
                           int* __restrict__ row_ptr, int* __restrict__ cursor) {
    __shared__ int s[256];
    int t = threadIdx.x;
    int i = blockIdx.x * 256 + t;
    s[t] = (i < N_NODES) ? cnt[i] : 0;
    __syncthreads();
    for (int off = 1; off < 256; off <<= 1) {
        int tmp = (t >= off) ? s[t - off] : 0;
        __syncthreads();
        s[t] += tmp;
        __syncthreads();
    }
    int excl = blockSums[blockIdx.x] + ((t > 0) ? s[t - 1] : 0);
    if (i < N_NODES) { row_ptr[i] = excl; cursor[i] = excl; }
    if (i == 0) row_ptr[N_NODES] = N_EDGES;
}

__global__ void fill_kernel(const int* __restrict__ srcv, const int* __restrict__ dstv,
                            int* __restrict__ cursor, ushort* __restrict__ csr_src) {
    int e = blockIdx.x * 256 + threadIdx.x;
    if (e < N_EDGES) {
        int pos = atomicAdd(&cursor[dstv[e]], 1);
        csr_src[pos] = (ushort)srcv[e];
    }
}

// ---------- Y = bf16(h @ Wl), Z = f32(h @ Wr) via MFMA, fp32 input ----------
template <int FIN>
__global__ void linYZ_kernel(const float* __restrict__ h, const float* __restrict__ Wl,
                             const float* __restrict__ Wr,
                             ushort* __restrict__ Y, float* __restrict__ Z) {
    constexpr int KT = FIN / 32;
    int wave = (blockIdx.x * 256 + threadIdx.x) >> 6;
    int lane = threadIdx.x & 63;
    int col = lane & 15;
    int quad = lane >> 4;
    int nwaves = gridDim.x * 4;

    bf16x8 bl_frag[KT][4], br_frag[KT][4];
#pragma unroll
    for (int kt = 0; kt < KT; ++kt)
#pragma unroll
        for (int nt = 0; nt < 4; ++nt) {
            bf16x8 tl, tr;
#pragma unroll
            for (int j = 0; j < 8; ++j) {
                int row = kt * 32 + quad * 8 + j;
                tl[j] = (short)f2bf(Wl[row * D_H + nt * 16 + col]);
                tr[j] = (short)f2bf(Wr[row * D_H + nt * 16 + col]);
            }
            bl_frag[kt][nt] = tl;
            br_frag[kt][nt] = tr;
        }

    for (int m0 = wave * 16; m0 < N_NODES; m0 += nwaves * 16) {
        f32x4 accl0 = {0.f,0.f,0.f,0.f}, accl1 = accl0, accl2 = accl0, accl3 = accl0;
        f32x4 accr0 = accl0, accr1 = accl0, accr2 = accl0, accr3 = accl0;
        const float* arow = h + (size_t)(m0 + col) * FIN + quad * 8;
#pragma unroll
        for (int kt = 0; kt < KT; ++kt) {
            float4 a_lo = *reinterpret_cast<const float4*>(arow + kt * 32);
            float4 a_hi = *reinterpret_cast<const float4*>(arow + kt * 32 + 4);
            bf16x8 a;
            a[0] = (short)f2bf(a_lo.x); a[1] = (short)f2bf(a_lo.y);
            a[2] = (short)f2bf(a_lo.z); a[3] = (short)f2bf(a_lo.w);
            a[4] = (short)f2bf(a_hi.x); a[5] = (short)f2bf(a_hi.y);
            a[6] = (short)f2bf(a_hi.z); a[7] = (short)f2bf(a_hi.w);
            accl0 = __builtin_amdgcn_mfma_f32_16x16x32_bf16(a, bl_frag[kt][0], accl0, 0, 0, 0);
            accl1 = __builtin_amdgcn_mfma_f32_16x16x32_bf16(a, bl_frag[kt][1], accl1, 0, 0, 0);
            accl2 = __builtin_amdgcn_mfma_f32_16x16x32_bf16(a, bl_frag[kt][2], accl2, 0, 0, 0);
            accl3 = __builtin_amdgcn_mfma_f32_16x16x32_bf16(a, bl_frag[kt][3], accl3, 0, 0, 0);
            accr0 = __builtin_amdgcn_mfma_f32_16x16x32_bf16(a, br_frag[kt][0], accr0, 0, 0, 0);
            accr1 = __builtin_amdgcn_mfma_f32_16x16x32_bf16(a, br_frag[kt][1], accr1, 0, 0, 0);
            accr2 = __builtin_amdgcn_mfma_f32_16x16x32_bf16(a, br_frag[kt][2], accr2, 0, 0, 0);
            accr3 = __builtin_amdgcn_mfma_f32_16x16x32_bf16(a, br_frag[kt][3], accr3, 0, 0, 0);
        }
#pragma unroll
        for (int reg = 0; reg < 4; ++reg) {
            size_t r = (size_t)(m0 + quad * 4 + reg) * D_H;
            ushort* yp = Y + r;
            yp[0 * 16 + col] = f2bf(accl0[reg]);
            yp[1 * 16 + col] = f2bf(accl1[reg]);
            yp[2 * 16 + col] = f2bf(accl2[reg]);
            yp[3 * 16 + col] = f2bf(accl3[reg]);
            float* zp = Z + r;
            zp[0 * 16 + col] = accr0[reg];
            zp[1 * 16 + col] = accr1[reg];
            zp[2 * 16 + col] = accr2[reg];
            zp[3 * 16 + col] = accr3[reg];
        }
    }
}

// ---------- per-node: agg = mean_{src} Y[src]; out = elu(agg + bl + Z[node]) ----------
// FUSE_PROJ: layer-3 variant also emits ps = out@Wp_top, pd = out@Wp_bot
template <bool FUSE_PROJ>
__global__ void gather_kernel(const ushort* __restrict__ Y, const float* __restrict__ Z,
                              const float* __restrict__ bl,
                              const int* __restrict__ row_ptr, const ushort* __restrict__ csr_src,
                              float* __restrict__ out,
                              const float* __restrict__ Wp,
                              float* __restrict__ ps, float* __restrict__ pd) {
    int node = (blockIdx.x << 2) + (threadIdx.x >> 6);
    int lane = threadIdx.x & 63;
    if (node >= N_NODES) return;
    int g = lane >> 4;
    int l = lane & 15;

    int beg = row_ptr[node];
    int deg = row_ptr[node + 1] - beg;
    float a0 = 0.f, a1 = 0.f, a2 = 0.f, a3 = 0.f;
    const uint2* __restrict__ Y2 = reinterpret_cast<const uint2*>(Y);  // 16 uint2 per row

    for (int base = 0; base < deg; base += 64) {
        int wend = deg - base; if (wend > 64) wend = 64;
        int mye = base + lane;
        int idxv = (mye < deg) ? (int)csr_src[beg + mye] : 0;
        for (int k = 0; k < wend; k += 16) {
            int e0 = k + g, e1 = k + 4 + g, e2 = k + 8 + g, e3 = k + 12 + g;
            int s0 = __shfl(idxv, e0);
            int s1 = __shfl(idxv, e1);
            int s2 = __shfl(idxv, e2);
            int s3 = __shfl(idxv, e3);
            bool v0 = e0 < wend, v1 = e1 < wend, v2 = e2 < wend, v3 = e3 < wend;
            uint2 r0, r1, r2, r3;
            if (v0) r0 = Y2[s0 * 16 + l];
            if (v1) r1 = Y2[s1 * 16 + l];
            if (v2) r2 = Y2[s2 * 16 + l];
            if (v3) r3 = Y2[s3 * 16 + l];
            if (v0) { a0 += bf16_lo(r0.x); a1 += bf16_hi(r0.x); a2 += bf16_lo(r0.y); a3 += bf16_hi(r0.y); }
            if (v1) { a0 += bf16_lo(r1.x); a1 += bf16_hi(r1.x); a2 += bf16_lo(r1.y); a3 += bf16_hi(r1.y); }
            if (v2) { a0 += bf16_lo(r2.x); a1 += bf16_hi(r2.x); a2 += bf16_lo(r2.y); a3 += bf16_hi(r2.y); }
            if (v3) { a0 += bf16_lo(r3.x); a1 += bf16_hi(r3.x); a2 += bf16_lo(r3.y); a3 += bf16_hi(r3.y); }
        }
    }

    a0 += __shfl_xor(a0, 16); a0 += __shfl_xor(a0, 32);
    a1 += __shfl_xor(a1, 16); a1 += __shfl_xor(a1, 32);
    a2 += __shfl_xor(a2, 16); a2 += __shfl_xor(a2, 32);
    a3 += __shfl_xor(a3, 16); a3 += __shfl_xor(a3, 32);

    if (g == 0) {
        float inv = 1.0f / fmaxf((float)deg, 1.0f);
        float4 b = reinterpret_cast<const float4*>(bl)[l];
        float4 zv = reinterpret_cast<const float4*>(Z + (size_t)node * D_H)[l];
        float v0 = a0 * inv + b.x + zv.x;
        float v1 = a1 * inv + b.y + zv.y;
        float v2 = a2 * inv + b.z + zv.z;
        float v3 = a3 * inv + b.w + zv.w;
        float4 o;
        o.x = v0 > 0.f ? v0 : expm1f(v0);
        o.y = v1 > 0.f ? v1 : expm1f(v1);
        o.z = v2 > 0.f ? v2 : expm1f(v2);
        o.w = v3 > 0.f ? v3 : expm1f(v3);
        reinterpret_cast<float4*>(out + (size_t)node * D_H)[l] = o;

        if (FUSE_PROJ) {
            float p0 = 0.f, p1 = 0.f, p2 = 0.f, p3 = 0.f;
            float q0 = 0.f, q1 = 0.f, q2 = 0.f, q3 = 0.f;
            float ov[4] = {o.x, o.y, o.z, o.w};
#pragma unroll
            for (int j = 0; j < 4; ++j) {
                int k = 4 * l + j;
                float4 wt = reinterpret_cast<const float4*>(Wp)[k];         // Wp[k][0..3]
                float4 wb = reinterpret_cast<const float4*>(Wp)[D_H + k];   // Wp[64+k][0..3]
                p0 += ov[j] * wt.x; p1 += ov[j] * wt.y; p2 += ov[j] * wt.z; p3 += ov[j] * wt.w;
                q0 += ov[j] * wb.x; q1 += ov[j] * wb.y; q2 += ov[j] * wb.z; q3 += ov[j] * wb.w;
            }
#pragma unroll
            for (int off = 1; off < 16; off <<= 1) {
                p0 += __shfl_xor(p0, off); p1 += __shfl_xor(p1, off);
                p2 += __shfl_xor(p2, off); p3 += __shfl_xor(p3, off);
                q0 += __shfl_xor(q0, off); q1 += __shfl_xor(q1, off);
                q2 += __shfl_xor(q2, off); q3 += __shfl_xor(q3, off);
            }
            if (l == 0) {
                float4 pv; pv.x = p0; pv.y = p1; pv.z = p2; pv.w = p3;
                float4 qv; qv.x = q0; qv.y = q1; qv.z = q2; qv.w = q3;
                reinterpret_cast<float4*>(ps)[node] = pv;
                reinterpret_cast<float4*>(pd)[node] = qv;
            }
        }
    }
}

__global__ void edge_final_kernel(const int* __restrict__ srcv, const int* __restrict__ dstv,
                                  const float* __restrict__ ps, const float* __restrict__ pd,
                                  const float* __restrict__ bp, float* __restrict__ out) {
    int e = blockIdx.x * 256 + threadIdx.x;
    if (e >= N_EDGES) return;
    float4 a = reinterpret_cast<const float4*>(ps)[srcv[e]];
    float4 b = reinterpret_cast<const float4*>(pd)[dstv[e]];
    float4 o;
    o.x = a.x + b.x + bp[0];
    o.y = a.y + b.y + bp[1];
    o.z = a.z + b.z + bp[2];
    o.w = a.w + b.w + bp[3];
    reinterpret_cast<float4*>(out)[e] = o;
}

extern "C" void kernel_launch(void* const* d_in, const int* in_sizes, int n_in,
                              void* d_out, int out_size, void* d_ws, size_t ws_size,
                              hipStream_t stream) {
    const float* x   = (const float*)d_in[0];
    const int*   ei  = (const int*)d_in[1];
    const float* Wl1 = (const float*)d_in[2];
    const float* bl1 = (const float*)d_in[3];
    const float* Wr1 = (const float*)d_in[4];
    const float* Wl2 = (const float*)d_in[5];
    const float* bl2 = (const float*)d_in[6];
    const float* Wr2 = (const float*)d_in[7];
    const float* Wl3 = (const float*)d_in[8];
    const float* bl3 = (const float*)d_in[9];
    const float* Wr3 = (const float*)d_in[10];
    const float* Wp  = (const float*)d_in[11];
    const float* bp  = (const float*)d_in[12];
    float* out = (float*)d_out;

    const int* srcv = ei;
    const int* dstv = ei + N_EDGES;

    // ---- workspace carve-up ----
    int*   cnt       = (int*)d_ws;                     // 50000
    int*   blockSums = cnt + 50000;                    // 256
    int*   row_ptr   = blockSums + 256;                // 50001
    int*   cursor    = row_ptr + 50001;                // 50000
    ushort* csr_src  = (ushort*)(cursor + 50000);      // 800000 ushort = 1.6 MB
    ushort* Y = (ushort*)(((uintptr_t)(csr_src + 800000) + 127) & ~(uintptr_t)127); // 3.2M bf16
    float* Z  = (float*)(((uintptr_t)(Y + (size_t)N_NODES * D_H) + 15) & ~(uintptr_t)15); // 3.2M f
    float* H1 = Z + (size_t)N_NODES * D_H;
    float* H2 = H1 + (size_t)N_NODES * D_H;
    float* ps = H2 + (size_t)N_NODES * D_H;
    float* pd = ps + (size_t)N_NODES * 4;

    // ---- CSR build ----
    hipMemsetAsync(cnt, 0, N_NODES * sizeof(int), stream);
    hist_kernel<<<(N_EDGES + 255) / 256, 256, 0, stream>>>(dstv, cnt);
    scan_partial<<<SCAN_BLOCKS, 256, 0, stream>>>(cnt, blockSums);
    scan_sums<<<1, 256, 0, stream>>>(blockSums);
    scan_final<<<SCAN_BLOCKS, 256, 0, stream>>>(cnt, blockSums, row_ptr, cursor);
    fill_kernel<<<(N_EDGES + 255) / 256, 256, 0, stream>>>(srcv, dstv, cursor, csr_src);

    const int GATHER_GRID = (N_NODES + 3) / 4;
    const int MFMA_GRID = 256;

    // ---- layer 1 (FIN=128) ----
    linYZ_kernel<D_IN><<<MFMA_GRID, 256, 0, stream>>>(x, Wl1, Wr1, Y, Z);
    gather_kernel<false><<<GATHER_GRID, 256, 0, stream>>>(Y, Z, bl1, row_ptr, csr_src, H1,
                                                          nullptr, nullptr, nullptr);

    // ---- layer 2 (FIN=64) ----
    linYZ_kernel<D_H><<<MFMA_GRID, 256, 0, stream>>>(H1, Wl2, Wr2, Y, Z);
    gather_kernel<false><<<GATHER_GRID, 256, 0, stream>>>(Y, Z, bl2, row_ptr, csr_src, H2,
                                                          nullptr, nullptr, nullptr);

    // ---- layer 3 (FIN=64), fused output projection ----
    linYZ_kernel<D_H><<<MFMA_GRID, 256, 0, stream>>>(H2, Wl3, Wr3, Y, Z);
    gather_kernel<true><<<GATHER_GRID, 256, 0, stream>>>(Y, Z, bl3, row_ptr, csr_src, H1,
                                                         Wp, ps, pd);

    // ---- edge output: out[e] = ps[src] + pd[dst] + bp ----
    edge_final_kernel<<<(N_EDGES + 255) / 256, 256, 0, stream>>>(srcv, dstv, ps, pd, bp, out);
}

// Round 8
// 322.120 us; speedup vs baseline: 1.1861x; 1.0496x over previous
//
#include <hip/hip_runtime.h>
#include <hip/hip_bf16.h>

#define N_NODES 50000
#define N_EDGES 800000
#define D_IN 128
#define D_H 64
#define SCAN_BLOCKS 196   // ceil(50000/256)

// W-fragment table offsets (in ushorts): [kt][nt][lane][8] per matrix
#define F1L 0
#define F1R 8192
#define F2L 16384
#define F2R 20480
#define F3L 24576
#define F3R 28672
#define FRAG_TOTAL 32768  // 64 KB

typedef short bf16x8 __attribute__((ext_vector_type(8)));
typedef float f32x4 __attribute__((ext_vector_type(4)));

__device__ __forceinline__ ushort f2bf(float f) {
    __hip_bfloat16 b = __float2bfloat16(f);
    return *reinterpret_cast<ushort*>(&b);
}
__device__ __forceinline__ float bf16_lo(unsigned int u) { return __uint_as_float(u << 16); }
__device__ __forceinline__ float bf16_hi(unsigned int u) { return __uint_as_float(u & 0xffff0000u); }

// ---------- CSR build ----------
__global__ void hist_kernel(const int* __restrict__ dstv, int* __restrict__ cnt) {
    int e = blockIdx.x * 256 + threadIdx.x;
    if (e < N_EDGES) atomicAdd(&cnt[dstv[e]], 1);
}

__global__ void scan_partial(const int* __restrict__ cnt, int* __restrict__ blockSums) {
    __shared__ int s[256];
    int i = blockIdx.x * 256 + threadIdx.x;
    s[threadIdx.x] = (i < N_NODES) ? cnt[i] : 0;
    __syncthreads();
    for (int off = 128; off > 0; off >>= 1) {
        if (threadIdx.x < off) s[threadIdx.x] += s[threadIdx.x + off];
        __syncthreads();
    }
    if (threadIdx.x == 0) blockSums[blockIdx.x] = s[0];
}

__global__ void scan_sums(int* __restrict__ blockSums) {
    __shared__ int s[256];
    int t = threadIdx.x;
    s[t] = (t < SCAN_BLOCKS) ? blockSums[t] : 0;
    __syncthreads();
    for (int off = 1; off < 256; off <<= 1) {
        int tmp = (t >= off) ? s[t - off] : 0;
        __syncthreads();
        s[t] += tmp;
        __syncthreads();
    }
    if (t < SCAN_BLOCKS) blockSums[t] = (t > 0) ? s[t - 1] : 0;
}

__global__ void scan_final(const int* __restrict__ cnt, const int* __restrict__ blockSums,
                           int* __restrict__ row_ptr, int* __restrict__ cursor) {
    __shared__ int s[256];
    int t = threadIdx.x;
    int i = blockIdx.x * 256 + t;
    s[t] = (i < N_NODES) ? cnt[i] : 0;
    __syncthreads();
    for (int off = 1; off < 256; off <<= 1) {
        int tmp = (t >= off) ? s[t - off] : 0;
        __syncthreads();
        s[t] += tmp;
        __syncthreads();
    }
    int excl = blockSums[blockIdx.x] + ((t > 0) ? s[t - 1] : 0);
    if (i < N_NODES) { row_ptr[i] = excl; cursor[i] = excl; }
    if (i == 0) row_ptr[N_NODES] = N_EDGES;
}

__global__ void fill_kernel(const int* __restrict__ srcv, const int* __restrict__ dstv,
                            int* __restrict__ cursor, ushort* __restrict__ csr_src) {
    int e = blockIdx.x * 256 + threadIdx.x;
    if (e < N_EDGES) {
        int pos = atomicAdd(&cursor[dstv[e]], 1);
        csr_src[pos] = (ushort)srcv[e];
    }
}

// ---------- precompute bf16 W-fragments in MFMA B-operand order ----------
// frag[fid] (16 B) = W[(kt*32 + quad*8 + j)*64 + nt*16 + col], j=0..7
// fid = base + (kt*4+nt)*64 + lane
__global__ void build_frags_kernel(const float* __restrict__ Wl1, const float* __restrict__ Wr1,
                                   const float* __restrict__ Wl2, const float* __restrict__ Wr2,
                                   const float* __restrict__ Wl3, const float* __restrict__ Wr3,
                                   ushort* __restrict__ frag) {
    int fid = blockIdx.x * 256 + threadIdx.x;  // 0..4095
    const float* W;
    int base;
    if (fid < 1024)      { W = Wl1; base = 0; }
    else if (fid < 2048) { W = Wr1; base = 1024; }
    else if (fid < 2560) { W = Wl2; base = 2048; }
    else if (fid < 3072) { W = Wr2; base = 2560; }
    else if (fid < 3584) { W = Wl3; base = 3072; }
    else                 { W = Wr3; base = 3584; }
    int local = fid - base;
    int lane = local & 63;
    int ktnt = local >> 6;
    int kt = ktnt >> 2, nt = ktnt & 3;
    int quad = lane >> 4, col = lane & 15;
    unsigned int w0, w1, w2, w3;
    ushort t0 = f2bf(W[(kt * 32 + quad * 8 + 0) * D_H + nt * 16 + col]);
    ushort t1 = f2bf(W[(kt * 32 + quad * 8 + 1) * D_H + nt * 16 + col]);
    ushort t2 = f2bf(W[(kt * 32 + quad * 8 + 2) * D_H + nt * 16 + col]);
    ushort t3 = f2bf(W[(kt * 32 + quad * 8 + 3) * D_H + nt * 16 + col]);
    ushort t4 = f2bf(W[(kt * 32 + quad * 8 + 4) * D_H + nt * 16 + col]);
    ushort t5 = f2bf(W[(kt * 32 + quad * 8 + 5) * D_H + nt * 16 + col]);
    ushort t6 = f2bf(W[(kt * 32 + quad * 8 + 6) * D_H + nt * 16 + col]);
    ushort t7 = f2bf(W[(kt * 32 + quad * 8 + 7) * D_H + nt * 16 + col]);
    w0 = (unsigned int)t0 | ((unsigned int)t1 << 16);
    w1 = (unsigned int)t2 | ((unsigned int)t3 << 16);
    w2 = (unsigned int)t4 | ((unsigned int)t5 << 16);
    w3 = (unsigned int)t6 | ((unsigned int)t7 << 16);
    uint4 v; v.x = w0; v.y = w1; v.z = w2; v.w = w3;
    *reinterpret_cast<uint4*>(frag + (size_t)fid * 8) = v;
}

// ---------- Y = bf16(h @ Wl), Z = f32(h @ Wr) via MFMA, fp32 input ----------
// one wave = one 16-row M-tile, all 64 output cols (4 n-tiles) for both products.
// B-fragments come pre-packed from the frag table (16 B vector loads).
template <int FIN>
__global__ void linYZ_kernel(const float* __restrict__ h,
                             const ushort* __restrict__ fragWl, const ushort* __restrict__ fragWr,
                             ushort* __restrict__ Y, float* __restrict__ Z) {
    constexpr int KT = FIN / 32;
    int wave = (blockIdx.x * 256 + threadIdx.x) >> 6;
    int lane = threadIdx.x & 63;
    int col = lane & 15;
    int quad = lane >> 4;
    int m0 = wave * 16;
    if (m0 >= N_NODES) return;

    bf16x8 bl_frag[KT][4], br_frag[KT][4];
#pragma unroll
    for (int kt = 0; kt < KT; ++kt)
#pragma unroll
        for (int nt = 0; nt < 4; ++nt) {
            size_t off = (size_t)((kt * 4 + nt) * 64 + lane) * 8;
            bl_frag[kt][nt] = __builtin_bit_cast(bf16x8,
                *reinterpret_cast<const uint4*>(fragWl + off));
            br_frag[kt][nt] = __builtin_bit_cast(bf16x8,
                *reinterpret_cast<const uint4*>(fragWr + off));
        }

    f32x4 accl0 = {0.f,0.f,0.f,0.f}, accl1 = accl0, accl2 = accl0, accl3 = accl0;
    f32x4 accr0 = accl0, accr1 = accl0, accr2 = accl0, accr3 = accl0;
    const float* arow = h + (size_t)(m0 + col) * FIN + quad * 8;
#pragma unroll
    for (int kt = 0; kt < KT; ++kt) {
        float4 a_lo = *reinterpret_cast<const float4*>(arow + kt * 32);
        float4 a_hi = *reinterpret_cast<const float4*>(arow + kt * 32 + 4);
        bf16x8 a;
        a[0] = (short)f2bf(a_lo.x); a[1] = (short)f2bf(a_lo.y);
        a[2] = (short)f2bf(a_lo.z); a[3] = (short)f2bf(a_lo.w);
        a[4] = (short)f2bf(a_hi.x); a[5] = (short)f2bf(a_hi.y);
        a[6] = (short)f2bf(a_hi.z); a[7] = (short)f2bf(a_hi.w);
        accl0 = __builtin_amdgcn_mfma_f32_16x16x32_bf16(a, bl_frag[kt][0], accl0, 0, 0, 0);
        accl1 = __builtin_amdgcn_mfma_f32_16x16x32_bf16(a, bl_frag[kt][1], accl1, 0, 0, 0);
        accl2 = __builtin_amdgcn_mfma_f32_16x16x32_bf16(a, bl_frag[kt][2], accl2, 0, 0, 0);
        accl3 = __builtin_amdgcn_mfma_f32_16x16x32_bf16(a, bl_frag[kt][3], accl3, 0, 0, 0);
        accr0 = __builtin_amdgcn_mfma_f32_16x16x32_bf16(a, br_frag[kt][0], accr0, 0, 0, 0);
        accr1 = __builtin_amdgcn_mfma_f32_16x16x32_bf16(a, br_frag[kt][1], accr1, 0, 0, 0);
        accr2 = __builtin_amdgcn_mfma_f32_16x16x32_bf16(a, br_frag[kt][2], accr2, 0, 0, 0);
        accr3 = __builtin_amdgcn_mfma_f32_16x16x32_bf16(a, br_frag[kt][3], accr3, 0, 0, 0);
    }
#pragma unroll
    for (int reg = 0; reg < 4; ++reg) {
        size_t r = (size_t)(m0 + quad * 4 + reg) * D_H;
        ushort* yp = Y + r;
        yp[0 * 16 + col] = f2bf(accl0[reg]);
        yp[1 * 16 + col] = f2bf(accl1[reg]);
        yp[2 * 16 + col] = f2bf(accl2[reg]);
        yp[3 * 16 + col] = f2bf(accl3[reg]);
        float* zp = Z + r;
        zp[0 * 16 + col] = accr0[reg];
        zp[1 * 16 + col] = accr1[reg];
        zp[2 * 16 + col] = accr2[reg];
        zp[3 * 16 + col] = accr3[reg];
    }
}

// ---------- per-node: agg = mean_{src} Y[src]; out = elu(agg + bl + Z[node]) ----------
// FUSE_PROJ: layer-3 variant also emits ps = out@Wp_top, pd = out@Wp_bot
template <bool FUSE_PROJ>
__global__ void gather_kernel(const ushort* __restrict__ Y, const float* __restrict__ Z,
                              const float* __restrict__ bl,
                              const int* __restrict__ row_ptr, const ushort* __restrict__ csr_src,
                              float* __restrict__ out,
                              const float* __restrict__ Wp,
                              float* __restrict__ ps, float* __restrict__ pd) {
    int node = (blockIdx.x << 2) + (threadIdx.x >> 6);
    int lane = threadIdx.x & 63;
    if (node >= N_NODES) return;
    int g = lane >> 4;
    int l = lane & 15;

    int beg = row_ptr[node];
    int deg = row_ptr[node + 1] - beg;
    float a0 = 0.f, a1 = 0.f, a2 = 0.f, a3 = 0.f;
    const uint2* __restrict__ Y2 = reinterpret_cast<const uint2*>(Y);  // 16 uint2 per row

    for (int base = 0; base < deg; base += 64) {
        int wend = deg - base; if (wend > 64) wend = 64;
        int mye = base + lane;
        int idxv = (mye < deg) ? (int)csr_src[beg + mye] : 0;
        for (int k = 0; k < wend; k += 16) {
            int e0 = k + g, e1 = k + 4 + g, e2 = k + 8 + g, e3 = k + 12 + g;
            int s0 = __shfl(idxv, e0);
            int s1 = __shfl(idxv, e1);
            int s2 = __shfl(idxv, e2);
            int s3 = __shfl(idxv, e3);
            bool v0 = e0 < wend, v1 = e1 < wend, v2 = e2 < wend, v3 = e3 < wend;
            uint2 r0, r1, r2, r3;
            if (v0) r0 = Y2[s0 * 16 + l];
            if (v1) r1 = Y2[s1 * 16 + l];
            if (v2) r2 = Y2[s2 * 16 + l];
            if (v3) r3 = Y2[s3 * 16 + l];
            if (v0) { a0 += bf16_lo(r0.x); a1 += bf16_hi(r0.x); a2 += bf16_lo(r0.y); a3 += bf16_hi(r0.y); }
            if (v1) { a0 += bf16_lo(r1.x); a1 += bf16_hi(r1.x); a2 += bf16_lo(r1.y); a3 += bf16_hi(r1.y); }
            if (v2) { a0 += bf16_lo(r2.x); a1 += bf16_hi(r2.x); a2 += bf16_lo(r2.y); a3 += bf16_hi(r2.y); }
            if (v3) { a0 += bf16_lo(r3.x); a1 += bf16_hi(r3.x); a2 += bf16_lo(r3.y); a3 += bf16_hi(r3.y); }
        }
    }

    a0 += __shfl_xor(a0, 16); a0 += __shfl_xor(a0, 32);
    a1 += __shfl_xor(a1, 16); a1 += __shfl_xor(a1, 32);
    a2 += __shfl_xor(a2, 16); a2 += __shfl_xor(a2, 32);
    a3 += __shfl_xor(a3, 16); a3 += __shfl_xor(a3, 32);

    if (g == 0) {
        float inv = 1.0f / fmaxf((float)deg, 1.0f);
        float4 b = reinterpret_cast<const float4*>(bl)[l];
        float4 zv = reinterpret_cast<const float4*>(Z + (size_t)node * D_H)[l];
        float v0 = a0 * inv + b.x + zv.x;
        float v1 = a1 * inv + b.y + zv.y;
        float v2 = a2 * inv + b.z + zv.z;
        float v3 = a3 * inv + b.w + zv.w;
        float4 o;
        o.x = v0 > 0.f ? v0 : expm1f(v0);
        o.y = v1 > 0.f ? v1 : expm1f(v1);
        o.z = v2 > 0.f ? v2 : expm1f(v2);
        o.w = v3 > 0.f ? v3 : expm1f(v3);
        reinterpret_cast<float4*>(out + (size_t)node * D_H)[l] = o;

        if (FUSE_PROJ) {
            float p0 = 0.f, p1 = 0.f, p2 = 0.f, p3 = 0.f;
            float q0 = 0.f, q1 = 0.f, q2 = 0.f, q3 = 0.f;
            float ov[4] = {o.x, o.y, o.z, o.w};
#pragma unroll
            for (int j = 0; j < 4; ++j) {
                int k = 4 * l + j;
                float4 wt = reinterpret_cast<const float4*>(Wp)[k];         // Wp[k][0..3]
                float4 wb = reinterpret_cast<const float4*>(Wp)[D_H + k];   // Wp[64+k][0..3]
                p0 += ov[j] * wt.x; p1 += ov[j] * wt.y; p2 += ov[j] * wt.z; p3 += ov[j] * wt.w;
                q0 += ov[j] * wb.x; q1 += ov[j] * wb.y; q2 += ov[j] * wb.z; q3 += ov[j] * wb.w;
            }
#pragma unroll
            for (int off = 1; off < 16; off <<= 1) {
                p0 += __shfl_xor(p0, off); p1 += __shfl_xor(p1, off);
                p2 += __shfl_xor(p2, off); p3 += __shfl_xor(p3, off);
                q0 += __shfl_xor(q0, off); q1 += __shfl_xor(q1, off);
                q2 += __shfl_xor(q2, off); q3 += __shfl_xor(q3, off);
            }
            if (l == 0) {
                float4 pv; pv.x = p0; pv.y = p1; pv.z = p2; pv.w = p3;
                float4 qv; qv.x = q0; qv.y = q1; qv.z = q2; qv.w = q3;
                reinterpret_cast<float4*>(ps)[node] = pv;
                reinterpret_cast<float4*>(pd)[node] = qv;
            }
        }
    }
}

__global__ void edge_final_kernel(const int* __restrict__ srcv, const int* __restrict__ dstv,
                                  const float* __restrict__ ps, const float* __restrict__ pd,
                                  const float* __restrict__ bp, float* __restrict__ out) {
    int e = blockIdx.x * 256 + threadIdx.x;
    if (e >= N_EDGES) return;
    float4 a = reinterpret_cast<const float4*>(ps)[srcv[e]];
    float4 b = reinterpret_cast<const float4*>(pd)[dstv[e]];
    float4 o;
    o.x = a.x + b.x + bp[0];
    o.y = a.y + b.y + bp[1];
    o.z = a.z + b.z + bp[2];
    o.w = a.w + b.w + bp[3];
    reinterpret_cast<float4*>(out)[e] = o;
}

extern "C" void kernel_launch(void* const* d_in, const int* in_sizes, int n_in,
                              void* d_out, int out_size, void* d_ws, size_t ws_size,
                              hipStream_t stream) {
    const float* x   = (const float*)d_in[0];
    const int*   ei  = (const int*)d_in[1];
    const float* Wl1 = (const float*)d_in[2];
    const float* bl1 = (const float*)d_in[3];
    const float* Wr1 = (const float*)d_in[4];
    const float* Wl2 = (const float*)d_in[5];
    const float* bl2 = (const float*)d_in[6];
    const float* Wr2 = (const float*)d_in[7];
    const float* Wl3 = (const float*)d_in[8];
    const float* bl3 = (const float*)d_in[9];
    const float* Wr3 = (const float*)d_in[10];
    const float* Wp  = (const float*)d_in[11];
    const float* bp  = (const float*)d_in[12];
    float* out = (float*)d_out;

    const int* srcv = ei;
    const int* dstv = ei + N_EDGES;

    // ---- workspace carve-up ----
    int*   cnt       = (int*)d_ws;                     // 50000
    int*   blockSums = cnt + 50000;                    // 256
    int*   row_ptr   = blockSums + 256;                // 50001
    int*   cursor    = row_ptr + 50001;                // 50000
    ushort* csr_src  = (ushort*)(cursor + 50000);      // 800000 ushort
    ushort* wfrag = (ushort*)(((uintptr_t)(csr_src + 800000) + 127) & ~(uintptr_t)127); // 64 KB
    ushort* Y = (ushort*)(((uintptr_t)(wfrag + FRAG_TOTAL) + 127) & ~(uintptr_t)127);   // 3.2M bf16
    float* Z  = (float*)(((uintptr_t)(Y + (size_t)N_NODES * D_H) + 15) & ~(uintptr_t)15);
    float* H1 = Z + (size_t)N_NODES * D_H;
    float* H2 = H1 + (size_t)N_NODES * D_H;
    float* ps = H2 + (size_t)N_NODES * D_H;
    float* pd = ps + (size_t)N_NODES * 4;

    // ---- W fragments + CSR build ----
    hipMemsetAsync(cnt, 0, N_NODES * sizeof(int), stream);
    build_frags_kernel<<<16, 256, 0, stream>>>(Wl1, Wr1, Wl2, Wr2, Wl3, Wr3, wfrag);
    hist_kernel<<<(N_EDGES + 255) / 256, 256, 0, stream>>>(dstv, cnt);
    scan_partial<<<SCAN_BLOCKS, 256, 0, stream>>>(cnt, blockSums);
    scan_sums<<<1, 256, 0, stream>>>(blockSums);
    scan_final<<<SCAN_BLOCKS, 256, 0, stream>>>(cnt, blockSums, row_ptr, cursor);
    fill_kernel<<<(N_EDGES + 255) / 256, 256, 0, stream>>>(srcv, dstv, cursor, csr_src);

    const int GATHER_GRID = (N_NODES + 3) / 4;
    const int MFMA_GRID = (N_NODES / 16 + 3) / 4;  // 782 blocks, 1 tile/wave

    // ---- layer 1 (FIN=128) ----
    linYZ_kernel<D_IN><<<MFMA_GRID, 256, 0, stream>>>(x, wfrag + F1L, wfrag + F1R, Y, Z);
    gather_kernel<false><<<GATHER_GRID, 256, 0, stream>>>(Y, Z, bl1, row_ptr, csr_src, H1,
                                                          nullptr, nullptr, nullptr);

    // ---- layer 2 (FIN=64) ----
    linYZ_kernel<D_H><<<MFMA_GRID, 256, 0, stream>>>(H1, wfrag + F2L, wfrag + F2R, Y, Z);
    gather_kernel<false><<<GATHER_GRID, 256, 0, stream>>>(Y, Z, bl2, row_ptr, csr_src, H2,
                                                          nullptr, nullptr, nullptr);

    // ---- layer 3 (FIN=64), fused output projection ----
    linYZ_kernel<D_H><<<MFMA_GRID, 256, 0, stream>>>(H2, wfrag + F3L, wfrag + F3R, Y, Z);
    gather_kernel<true><<<GATHER_GRID, 256, 0, stream>>>(Y, Z, bl3, row_ptr, csr_src, H1,
                                                         Wp, ps, pd);

    // ---- edge output: out[e] = ps[src] + pd[dst] + bp ----
    edge_final_kernel<<<(N_EDGES + 255) / 256, 256, 0, stream>>>(srcv, dstv, ps, pd, bp, out);
}

// Round 9
// 306.176 us; speedup vs baseline: 1.2479x; 1.0521x over previous
//
#include <hip/hip_runtime.h>
#include <hip/hip_bf16.h>

#define N_NODES 50000
#define N_EDGES 800000
#define D_IN 128
#define D_H 64
#define SCAN_BLOCKS 196   // ceil(50000/256)
#define HIST_BLOCKS 3125  // N_EDGES/256
#define LIN1_BLOCKS 782   // ceil(3125 waves / 4)

// W-fragment table offsets (in ushorts): [kt][nt][lane][8] per matrix
#define F1L 0
#define F1R 8192
#define F2L 16384
#define F2R 20480
#define F3L 24576
#define F3R 28672
#define FRAG_TOTAL 32768  // 64 KB

typedef short bf16x8 __attribute__((ext_vector_type(8)));
typedef float f32x4 __attribute__((ext_vector_type(4)));

__device__ __forceinline__ ushort f2bf(float f) {
    __hip_bfloat16 b = __float2bfloat16(f);
    return *reinterpret_cast<ushort*>(&b);
}
__device__ __forceinline__ float bf16_lo(unsigned int u) { return __uint_as_float(u << 16); }
__device__ __forceinline__ float bf16_hi(unsigned int u) { return __uint_as_float(u & 0xffff0000u); }

// ---------- W-fragment build (device helper) ----------
__device__ __forceinline__ void build_frag_one(const float* __restrict__ W, int local,
                                               ushort* __restrict__ frag, int fid) {
    int lane = local & 63;
    int ktnt = local >> 6;
    int kt = ktnt >> 2, nt = ktnt & 3;
    int quad = lane >> 4, col = lane & 15;
    ushort t0 = f2bf(W[(kt * 32 + quad * 8 + 0) * D_H + nt * 16 + col]);
    ushort t1 = f2bf(W[(kt * 32 + quad * 8 + 1) * D_H + nt * 16 + col]);
    ushort t2 = f2bf(W[(kt * 32 + quad * 8 + 2) * D_H + nt * 16 + col]);
    ushort t3 = f2bf(W[(kt * 32 + quad * 8 + 3) * D_H + nt * 16 + col]);
    ushort t4 = f2bf(W[(kt * 32 + quad * 8 + 4) * D_H + nt * 16 + col]);
    ushort t5 = f2bf(W[(kt * 32 + quad * 8 + 5) * D_H + nt * 16 + col]);
    ushort t6 = f2bf(W[(kt * 32 + quad * 8 + 6) * D_H + nt * 16 + col]);
    ushort t7 = f2bf(W[(kt * 32 + quad * 8 + 7) * D_H + nt * 16 + col]);
    uint4 v;
    v.x = (unsigned int)t0 | ((unsigned int)t1 << 16);
    v.y = (unsigned int)t2 | ((unsigned int)t3 << 16);
    v.z = (unsigned int)t4 | ((unsigned int)t5 << 16);
    v.w = (unsigned int)t6 | ((unsigned int)t7 << 16);
    *reinterpret_cast<uint4*>(frag + (size_t)fid * 8) = v;
}

// ---------- K1: hist (3125 blocks) || build_frags (16 blocks) ----------
__global__ void hist_frags_kernel(const int* __restrict__ dstv, int* __restrict__ cnt,
                                  const float* __restrict__ Wl1, const float* __restrict__ Wr1,
                                  const float* __restrict__ Wl2, const float* __restrict__ Wr2,
                                  const float* __restrict__ Wl3, const float* __restrict__ Wr3,
                                  ushort* __restrict__ frag) {
    if (blockIdx.x < HIST_BLOCKS) {
        int e = blockIdx.x * 256 + threadIdx.x;
        if (e < N_EDGES) atomicAdd(&cnt[dstv[e]], 1);
    } else {
        int fid = (blockIdx.x - HIST_BLOCKS) * 256 + threadIdx.x;  // 0..4095
        const float* W; int base;
        if (fid < 1024)      { W = Wl1; base = 0; }
        else if (fid < 2048) { W = Wr1; base = 1024; }
        else if (fid < 2560) { W = Wl2; base = 2048; }
        else if (fid < 3072) { W = Wr2; base = 2560; }
        else if (fid < 3584) { W = Wl3; base = 3072; }
        else                 { W = Wr3; base = 3584; }
        build_frag_one(W, fid - base, frag, fid);
    }
}

// ---------- K2: per-block partial sums ----------
__global__ void scan_partial(const int* __restrict__ cnt, int* __restrict__ blockSums) {
    __shared__ int s[256];
    int i = blockIdx.x * 256 + threadIdx.x;
    s[threadIdx.x] = (i < N_NODES) ? cnt[i] : 0;
    __syncthreads();
    for (int off = 128; off > 0; off >>= 1) {
        if (threadIdx.x < off) s[threadIdx.x] += s[threadIdx.x + off];
        __syncthreads();
    }
    if (threadIdx.x == 0) blockSums[blockIdx.x] = s[0];
}

// ---------- K3: fused (scan of blockSums redundantly per block) + final scan ----------
__global__ void scan_final(const int* __restrict__ cnt, const int* __restrict__ blockSums,
                           int* __restrict__ row_ptr, int* __restrict__ cursor) {
    __shared__ int s[256];
    __shared__ int bs[256];
    int t = threadIdx.x;
    bs[t] = (t < SCAN_BLOCKS) ? blockSums[t] : 0;
    int i = blockIdx.x * 256 + t;
    s[t] = (i < N_NODES) ? cnt[i] : 0;
    __syncthreads();
    // inclusive scan both arrays with the same ladder
    for (int off = 1; off < 256; off <<= 1) {
        int tmp1 = (t >= off) ? s[t - off] : 0;
        int tmp2 = (t >= off) ? bs[t - off] : 0;
        __syncthreads();
        s[t] += tmp1;
        bs[t] += tmp2;
        __syncthreads();
    }
    int blockExcl = (blockIdx.x > 0) ? bs[blockIdx.x - 1] : 0;
    int excl = blockExcl + ((t > 0) ? s[t - 1] : 0);
    if (i < N_NODES) { row_ptr[i] = excl; cursor[i] = excl; }
    if (i == 0) row_ptr[N_NODES] = N_EDGES;
}

// ---------- lin body: Y = bf16(h@Wl), Zb = bf16(h@Wr), one 16-row tile per wave ----------
template <int FIN, bool BF16IN>
__device__ __forceinline__ void lin_body(int gwave, int lane, const void* __restrict__ hin,
                                         const ushort* __restrict__ fragWl,
                                         const ushort* __restrict__ fragWr,
                                         ushort* __restrict__ Y, ushort* __restrict__ Zb) {
    constexpr int KT = FIN / 32;
    int m0 = gwave * 16;
    if (m0 >= N_NODES) return;
    int col = lane & 15;
    int quad = lane >> 4;

    bf16x8 blf[KT][4], brf[KT][4];
#pragma unroll
    for (int kt = 0; kt < KT; ++kt)
#pragma unroll
        for (int nt = 0; nt < 4; ++nt) {
            size_t off = (size_t)((kt * 4 + nt) * 64 + lane) * 8;
            blf[kt][nt] = __builtin_bit_cast(bf16x8, *reinterpret_cast<const uint4*>(fragWl + off));
            brf[kt][nt] = __builtin_bit_cast(bf16x8, *reinterpret_cast<const uint4*>(fragWr + off));
        }

    f32x4 accl0 = {0.f,0.f,0.f,0.f}, accl1 = accl0, accl2 = accl0, accl3 = accl0;
    f32x4 accr0 = accl0, accr1 = accl0, accr2 = accl0, accr3 = accl0;
#pragma unroll
    for (int kt = 0; kt < KT; ++kt) {
        bf16x8 a;
        if (BF16IN) {
            const ushort* arow = (const ushort*)hin + (size_t)(m0 + col) * FIN + quad * 8;
            a = __builtin_bit_cast(bf16x8, *reinterpret_cast<const uint4*>(arow + kt * 32));
        } else {
            const float* arow = (const float*)hin + (size_t)(m0 + col) * FIN + quad * 8;
            float4 a_lo = *reinterpret_cast<const float4*>(arow + kt * 32);
            float4 a_hi = *reinterpret_cast<const float4*>(arow + kt * 32 + 4);
            a[0] = (short)f2bf(a_lo.x); a[1] = (short)f2bf(a_lo.y);
            a[2] = (short)f2bf(a_lo.z); a[3] = (short)f2bf(a_lo.w);
            a[4] = (short)f2bf(a_hi.x); a[5] = (short)f2bf(a_hi.y);
            a[6] = (short)f2bf(a_hi.z); a[7] = (short)f2bf(a_hi.w);
        }
        accl0 = __builtin_amdgcn_mfma_f32_16x16x32_bf16(a, blf[kt][0], accl0, 0, 0, 0);
        accl1 = __builtin_amdgcn_mfma_f32_16x16x32_bf16(a, blf[kt][1], accl1, 0, 0, 0);
        accl2 = __builtin_amdgcn_mfma_f32_16x16x32_bf16(a, blf[kt][2], accl2, 0, 0, 0);
        accl3 = __builtin_amdgcn_mfma_f32_16x16x32_bf16(a, blf[kt][3], accl3, 0, 0, 0);
        accr0 = __builtin_amdgcn_mfma_f32_16x16x32_bf16(a, brf[kt][0], accr0, 0, 0, 0);
        accr1 = __builtin_amdgcn_mfma_f32_16x16x32_bf16(a, brf[kt][1], accr1, 0, 0, 0);
        accr2 = __builtin_amdgcn_mfma_f32_16x16x32_bf16(a, brf[kt][2], accr2, 0, 0, 0);
        accr3 = __builtin_amdgcn_mfma_f32_16x16x32_bf16(a, brf[kt][3], accr3, 0, 0, 0);
    }
#pragma unroll
    for (int reg = 0; reg < 4; ++reg) {
        size_t r = (size_t)(m0 + quad * 4 + reg) * D_H;
        ushort* yp = Y + r;
        yp[0 * 16 + col] = f2bf(accl0[reg]);
        yp[1 * 16 + col] = f2bf(accl1[reg]);
        yp[2 * 16 + col] = f2bf(accl2[reg]);
        yp[3 * 16 + col] = f2bf(accl3[reg]);
        ushort* zp = Zb + r;
        zp[0 * 16 + col] = f2bf(accr0[reg]);
        zp[1 * 16 + col] = f2bf(accr1[reg]);
        zp[2 * 16 + col] = f2bf(accr2[reg]);
        zp[3 * 16 + col] = f2bf(accr3[reg]);
    }
}

// ---------- K4: layer-1 linYZ (fp32 in, 782 blocks) || CSR fill (3125 blocks) ----------
__global__ void lin1_fill_kernel(const float* __restrict__ x, const ushort* __restrict__ wfrag,
                                 const int* __restrict__ srcv, const int* __restrict__ dstv,
                                 int* __restrict__ cursor, ushort* __restrict__ csr_src,
                                 ushort* __restrict__ Y, ushort* __restrict__ Zb) {
    if (blockIdx.x < LIN1_BLOCKS) {
        int gwave = (blockIdx.x * 256 + threadIdx.x) >> 6;
        lin_body<D_IN, false>(gwave, threadIdx.x & 63, x, wfrag + F1L, wfrag + F1R, Y, Zb);
    } else {
        int e = (blockIdx.x - LIN1_BLOCKS) * 256 + threadIdx.x;
        if (e < N_EDGES) {
            int pos = atomicAdd(&cursor[dstv[e]], 1);
            csr_src[pos] = (ushort)srcv[e];
        }
    }
}

// ---------- layers 2/3 linYZ (bf16 in) ----------
__global__ void linYZ_b_kernel(const ushort* __restrict__ hb, const ushort* __restrict__ fragWl,
                               const ushort* __restrict__ fragWr,
                               ushort* __restrict__ Y, ushort* __restrict__ Zb) {
    int gwave = (blockIdx.x * 256 + threadIdx.x) >> 6;
    lin_body<D_H, true>(gwave, threadIdx.x & 63, hb, fragWl, fragWr, Y, Zb);
}

// ---------- per-node: agg = mean_{src} Y[src]; o = elu(agg + bl + Zb[node]) ----------
// !FUSE_PROJ: writes o as bf16 to outb. FUSE_PROJ: writes ps/pd only (o is dead).
template <bool FUSE_PROJ>
__global__ void gather_kernel(const ushort* __restrict__ Y, const ushort* __restrict__ Zb,
                              const float* __restrict__ bl,
                              const int* __restrict__ row_ptr, const ushort* __restrict__ csr_src,
                              ushort* __restrict__ outb,
                              const float* __restrict__ Wp,
                              float* __restrict__ ps, float* __restrict__ pd) {
    int node = (blockIdx.x << 2) + (threadIdx.x >> 6);
    int lane = threadIdx.x & 63;
    if (node >= N_NODES) return;
    int g = lane >> 4;
    int l = lane & 15;

    int beg = row_ptr[node];
    int deg = row_ptr[node + 1] - beg;
    float a0 = 0.f, a1 = 0.f, a2 = 0.f, a3 = 0.f;
    const uint2* __restrict__ Y2 = reinterpret_cast<const uint2*>(Y);  // 16 uint2 per row

    for (int base = 0; base < deg; base += 64) {
        int wend = deg - base; if (wend > 64) wend = 64;
        int mye = base + lane;
        int idxv = (mye < deg) ? (int)csr_src[beg + mye] : 0;
        for (int k = 0; k < wend; k += 16) {
            int e0 = k + g, e1 = k + 4 + g, e2 = k + 8 + g, e3 = k + 12 + g;
            int s0 = __shfl(idxv, e0);
            int s1 = __shfl(idxv, e1);
            int s2 = __shfl(idxv, e2);
            int s3 = __shfl(idxv, e3);
            bool v0 = e0 < wend, v1 = e1 < wend, v2 = e2 < wend, v3 = e3 < wend;
            uint2 r0, r1, r2, r3;
            if (v0) r0 = Y2[s0 * 16 + l];
            if (v1) r1 = Y2[s1 * 16 + l];
            if (v2) r2 = Y2[s2 * 16 + l];
            if (v3) r3 = Y2[s3 * 16 + l];
            if (v0) { a0 += bf16_lo(r0.x); a1 += bf16_hi(r0.x); a2 += bf16_lo(r0.y); a3 += bf16_hi(r0.y); }
            if (v1) { a0 += bf16_lo(r1.x); a1 += bf16_hi(r1.x); a2 += bf16_lo(r1.y); a3 += bf16_hi(r1.y); }
            if (v2) { a0 += bf16_lo(r2.x); a1 += bf16_hi(r2.x); a2 += bf16_lo(r2.y); a3 += bf16_hi(r2.y); }
            if (v3) { a0 += bf16_lo(r3.x); a1 += bf16_hi(r3.x); a2 += bf16_lo(r3.y); a3 += bf16_hi(r3.y); }
        }
    }

    a0 += __shfl_xor(a0, 16); a0 += __shfl_xor(a0, 32);
    a1 += __shfl_xor(a1, 16); a1 += __shfl_xor(a1, 32);
    a2 += __shfl_xor(a2, 16); a2 += __shfl_xor(a2, 32);
    a3 += __shfl_xor(a3, 16); a3 += __shfl_xor(a3, 32);

    if (g == 0) {
        float inv = 1.0f / fmaxf((float)deg, 1.0f);
        float4 b = reinterpret_cast<const float4*>(bl)[l];
        uint2 zr = reinterpret_cast<const uint2*>(Zb)[node * 16 + l];
        float v0 = a0 * inv + b.x + bf16_lo(zr.x);
        float v1 = a1 * inv + b.y + bf16_hi(zr.x);
        float v2 = a2 * inv + b.z + bf16_lo(zr.y);
        float v3 = a3 * inv + b.w + bf16_hi(zr.y);
        float4 o;
        o.x = v0 > 0.f ? v0 : expm1f(v0);
        o.y = v1 > 0.f ? v1 : expm1f(v1);
        o.z = v2 > 0.f ? v2 : expm1f(v2);
        o.w = v3 > 0.f ? v3 : expm1f(v3);

        if constexpr (!FUSE_PROJ) {
            ushort4 ob;
            ob.x = f2bf(o.x); ob.y = f2bf(o.y); ob.z = f2bf(o.z); ob.w = f2bf(o.w);
            reinterpret_cast<ushort4*>(outb)[node * 16 + l] = ob;
        } else {
            float p0 = 0.f, p1 = 0.f, p2 = 0.f, p3 = 0.f;
            float q0 = 0.f, q1 = 0.f, q2 = 0.f, q3 = 0.f;
            float ov[4] = {o.x, o.y, o.z, o.w};
#pragma unroll
            for (int j = 0; j < 4; ++j) {
                int k = 4 * l + j;
                float4 wt = reinterpret_cast<const float4*>(Wp)[k];         // Wp[k][0..3]
                float4 wb = reinterpret_cast<const float4*>(Wp)[D_H + k];   // Wp[64+k][0..3]
                p0 += ov[j] * wt.x; p1 += ov[j] * wt.y; p2 += ov[j] * wt.z; p3 += ov[j] * wt.w;
                q0 += ov[j] * wb.x; q1 += ov[j] * wb.y; q2 += ov[j] * wb.z; q3 += ov[j] * wb.w;
            }
#pragma unroll
            for (int off = 1; off < 16; off <<= 1) {
                p0 += __shfl_xor(p0, off); p1 += __shfl_xor(p1, off);
                p2 += __shfl_xor(p2, off); p3 += __shfl_xor(p3, off);
                q0 += __shfl_xor(q0, off); q1 += __shfl_xor(q1, off);
                q2 += __shfl_xor(q2, off); q3 += __shfl_xor(q3, off);
            }
            if (l == 0) {
                float4 pv; pv.x = p0; pv.y = p1; pv.z = p2; pv.w = p3;
                float4 qv; qv.x = q0; qv.y = q1; qv.z = q2; qv.w = q3;
                reinterpret_cast<float4*>(ps)[node] = pv;
                reinterpret_cast<float4*>(pd)[node] = qv;
            }
        }
    }
}

__global__ void edge_final_kernel(const int* __restrict__ srcv, const int* __restrict__ dstv,
                                  const float* __restrict__ ps, const float* __restrict__ pd,
                                  const float* __restrict__ bp, float* __restrict__ out) {
    int e = blockIdx.x * 256 + threadIdx.x;
    if (e >= N_EDGES) return;
    float4 a = reinterpret_cast<const float4*>(ps)[srcv[e]];
    float4 b = reinterpret_cast<const float4*>(pd)[dstv[e]];
    float4 o;
    o.x = a.x + b.x + bp[0];
    o.y = a.y + b.y + bp[1];
    o.z = a.z + b.z + bp[2];
    o.w = a.w + b.w + bp[3];
    reinterpret_cast<float4*>(out)[e] = o;
}

extern "C" void kernel_launch(void* const* d_in, const int* in_sizes, int n_in,
                              void* d_out, int out_size, void* d_ws, size_t ws_size,
                              hipStream_t stream) {
    const float* x   = (const float*)d_in[0];
    const int*   ei  = (const int*)d_in[1];
    const float* Wl1 = (const float*)d_in[2];
    const float* bl1 = (const float*)d_in[3];
    const float* Wr1 = (const float*)d_in[4];
    const float* Wl2 = (const float*)d_in[5];
    const float* bl2 = (const float*)d_in[6];
    const float* Wr2 = (const float*)d_in[7];
    const float* Wl3 = (const float*)d_in[8];
    const float* bl3 = (const float*)d_in[9];
    const float* Wr3 = (const float*)d_in[10];
    const float* Wp  = (const float*)d_in[11];
    const float* bp  = (const float*)d_in[12];
    float* out = (float*)d_out;

    const int* srcv = ei;
    const int* dstv = ei + N_EDGES;

    // ---- workspace carve-up ----
    int*   cnt       = (int*)d_ws;                     // 50000
    int*   blockSums = cnt + 50000;                    // 256
    int*   row_ptr   = blockSums + 256;                // 50001
    int*   cursor    = row_ptr + 50001;                // 50000
    ushort* csr_src  = (ushort*)(cursor + 50000);      // 800000 ushort
    ushort* wfrag = (ushort*)(((uintptr_t)(csr_src + 800000) + 127) & ~(uintptr_t)127); // 64 KB
    ushort* Y   = (ushort*)(((uintptr_t)(wfrag + FRAG_TOTAL) + 127) & ~(uintptr_t)127); // 6.4 MB
    ushort* Zb  = Y + (size_t)N_NODES * D_H;           // 6.4 MB
    ushort* H1b = Zb + (size_t)N_NODES * D_H;          // 6.4 MB
    ushort* H2b = H1b + (size_t)N_NODES * D_H;         // 6.4 MB
    float* ps = (float*)(((uintptr_t)(H2b + (size_t)N_NODES * D_H) + 15) & ~(uintptr_t)15);
    float* pd = ps + (size_t)N_NODES * 4;

    // ---- K1: hist || frag build ----
    hipMemsetAsync(cnt, 0, N_NODES * sizeof(int), stream);
    hist_frags_kernel<<<HIST_BLOCKS + 16, 256, 0, stream>>>(dstv, cnt, Wl1, Wr1, Wl2, Wr2,
                                                            Wl3, Wr3, wfrag);
    // ---- K2/K3: scans ----
    scan_partial<<<SCAN_BLOCKS, 256, 0, stream>>>(cnt, blockSums);
    scan_final<<<SCAN_BLOCKS, 256, 0, stream>>>(cnt, blockSums, row_ptr, cursor);

    const int GATHER_GRID = (N_NODES + 3) / 4;

    // ---- K4: layer-1 linYZ || CSR fill ----
    lin1_fill_kernel<<<LIN1_BLOCKS + HIST_BLOCKS, 256, 0, stream>>>(x, wfrag, srcv, dstv,
                                                                    cursor, csr_src, Y, Zb);
    gather_kernel<false><<<GATHER_GRID, 256, 0, stream>>>(Y, Zb, bl1, row_ptr, csr_src, H1b,
                                                          nullptr, nullptr, nullptr);

    // ---- layer 2 ----
    linYZ_b_kernel<<<LIN1_BLOCKS, 256, 0, stream>>>(H1b, wfrag + F2L, wfrag + F2R, Y, Zb);
    gather_kernel<false><<<GATHER_GRID, 256, 0, stream>>>(Y, Zb, bl2, row_ptr, csr_src, H2b,
                                                          nullptr, nullptr, nullptr);

    // ---- layer 3, fused output projection (no H store) ----
    linYZ_b_kernel<<<LIN1_BLOCKS, 256, 0, stream>>>(H2b, wfrag + F3L, wfrag + F3R, Y, Zb);
    gather_kernel<true><<<GATHER_GRID, 256, 0, stream>>>(Y, Zb, bl3, row_ptr, csr_src, nullptr,
                                                         Wp, ps, pd);

    // ---- edge output: out[e] = ps[src] + pd[dst] + bp ----
    edge_final_kernel<<<(N_EDGES + 255) / 256, 256, 0, stream>>>(srcv, dstv, ps, pd, bp, out);
}